// Round 5
// baseline (264.940 us; speedup 1.0000x reference)
//
#include <hip/hip_runtime.h>
#include <hip/hip_bf16.h>

// Problem constants
#define B_  4
#define S_  2048
#define D_  256
#define H_  8
#define HD_ 32
#define K_  204          // int(2048 * 0.1)
#define SCALE_ 0.17677669529663687f  // 1/sqrt(32)

// ---- workspace layout (float offsets) ----
#define OFF_IMP    0          // 8192 floats
#define OFF_KG     8192       // 208896 floats [B,H,K,hd]
#define OFF_VG     217088     // 208896 floats
#define OFF_FLAGS  425984     // 8192 ints
#define OFF_KIDX   434176     // 1024 ints
#define OFF_Q      435200     // 2097152 floats [B*S, D]
#define OFF_AO     2532352    // 2097152 floats [B*S, D]

// ---------------- kernel 1: gate MLP -> importance logit ----------------
// 32 tokens per block (256 blocks). thread=(f=tid>>2, c=tid&3); weight regs
// reused across 32 tokens. sigmoid/gate_b2 skipped (monotone, ranking only).
__global__ __launch_bounds__(256) void gate_kernel(
    const float* __restrict__ x, const float* __restrict__ gw1,
    const float* __restrict__ gb1, const float* __restrict__ gw2, float* ws)
{
    const int t0 = blockIdx.x * 32;
    const int tid = threadIdx.x;
    __shared__ __align__(16) float xs[32 * D_];   // 32 KB
    __shared__ float hred[32 * 64];               // 8 KB

    const float4* src = (const float4*)(x + (size_t)t0 * D_);
    float4* dst = (float4*)xs;
    #pragma unroll
    for (int i = 0; i < 8; ++i) dst[tid + i * 256] = src[tid + i * 256];
    __syncthreads();

    const int c = tid & 3, f = tid >> 2;
    float4 wv[16];
    const float4* wr = (const float4*)(gw1 + (size_t)f * D_) + c;
    #pragma unroll
    for (int j = 0; j < 16; ++j) wv[j] = wr[j * 4];
    const float bb = gb1[f], g2 = gw2[f];

    #pragma unroll 4
    for (int tk = 0; tk < 32; ++tk) {
        const float4* xr = (const float4*)(xs + tk * D_) + c;
        float a = 0.0f;
        #pragma unroll
        for (int j = 0; j < 16; ++j) {
            float4 xv = xr[j * 4];
            a += wv[j].x*xv.x + wv[j].y*xv.y + wv[j].z*xv.z + wv[j].w*xv.w;
        }
        a += __shfl_xor(a, 1);
        a += __shfl_xor(a, 2);
        if (c == 0) hred[tk * 64 + f] = fmaxf(a + bb, 0.0f) * g2;
    }
    __syncthreads();

    // 256 threads = 32 tokens x 8 lanes
    const int tk = tid >> 3, l = tid & 7;
    float s = 0.0f;
    #pragma unroll
    for (int i = 0; i < 8; ++i) s += hred[tk * 64 + l + 8 * i];
    s += __shfl_xor(s, 1); s += __shfl_xor(s, 2); s += __shfl_xor(s, 4);
    if (l == 0) ws[OFF_IMP + t0 + tk] = s;
}

// ---------------- kernel 2a: exact rank -> kept flag (lax.top_k ties) ----------------
__global__ __launch_bounds__(256) void rank_kernel(const float* __restrict__ ws_imp, int* flags)
{
    const int b = blockIdx.x >> 3;
    const int i = (blockIdx.x & 7) * 256 + threadIdx.x;
    __shared__ __align__(16) float vs[S_];
    const float* src = ws_imp + b * S_;
    #pragma unroll
    for (int c = 0; c < S_/256; ++c) vs[threadIdx.x + c*256] = src[threadIdx.x + c*256];
    __syncthreads();

    const float vi = vs[i];
    int gt = 0, eq = 0;
    const float4* v4 = (const float4*)vs;
    for (int j4 = 0; j4 < S_/4; ++j4) {
        float4 w = v4[j4];
        int base = j4 * 4;
        gt += (w.x > vi); eq += (w.x == vi) && (base + 0 < i);
        gt += (w.y > vi); eq += (w.y == vi) && (base + 1 < i);
        gt += (w.z > vi); eq += (w.z == vi) && (base + 2 < i);
        gt += (w.w > vi); eq += (w.w == vi) && (base + 3 < i);
    }
    flags[b * S_ + i] = ((gt + eq) < K_) ? 1 : 0;
}

// ---------------- kernel 2b: scan flags -> compact sorted index list ----------------
__global__ __launch_bounds__(256) void emit_kernel(const int* __restrict__ flags, int* kidx)
{
    const int b = blockIdx.x;
    const int t = threadIdx.x;
    __shared__ int fl[S_];
    __shared__ int cs[256];
    const int* src = flags + b * S_;
    #pragma unroll
    for (int c = 0; c < S_/256; ++c) fl[t + c*256] = src[t + c*256];
    __syncthreads();

    int s = 0;
    #pragma unroll
    for (int c = 0; c < 8; ++c) s += fl[t*8 + c];
    cs[t] = s;
    __syncthreads();
    for (int off = 1; off < 256; off <<= 1) {
        int v = (t >= off) ? cs[t - off] : 0;
        __syncthreads();
        cs[t] += v;
        __syncthreads();
    }
    int pos = cs[t] - s;
    #pragma unroll
    for (int c = 0; c < 8; ++c) {
        int idx = t*8 + c;
        if (fl[idx]) { if (pos < K_) kidx[b * K_ + pos] = idx; ++pos; }
    }
}

// ---------------- kernel 3: K/V projection for kept keys (6 keys/block) ----------------
__global__ __launch_bounds__(256) void kv_kernel(
    const float* __restrict__ x, const float* __restrict__ w_in,
    const float* __restrict__ b_in, float* ws, const int* __restrict__ kidx)
{
    const int b = blockIdx.y, j0 = blockIdx.x * 6, tid = threadIdx.x;
    __shared__ __align__(16) float xs[6 * D_];
    __shared__ int toks[6];
    if (tid < 6) {
        int tk = kidx[b * K_ + j0 + tid];
        toks[tid] = min(max(tk, 0), S_ - 1);
    }
    __syncthreads();
    for (int i = tid; i < 6 * 64; i += 256) {
        const int kk = i >> 6, l = i & 63;
        ((float4*)xs)[i] = ((const float4*)(x + ((size_t)b * S_ + toks[kk]) * D_))[l];
    }
    __syncthreads();

    const int c = tid & 3, f = tid >> 2;
    #pragma unroll 1
    for (int fg = 0; fg < 8; ++fg) {
        const int eh = fg * 64 + f;
        float4 wv[16];
        const float4* wr = (const float4*)(w_in + (size_t)(D_ + eh) * D_) + c;
        #pragma unroll
        for (int j = 0; j < 16; ++j) wv[j] = wr[j * 4];
        float acc[6] = {0,0,0,0,0,0};
        #pragma unroll
        for (int j = 0; j < 16; ++j) {
            float4 w = wv[j];
            #pragma unroll
            for (int kk = 0; kk < 6; ++kk) {
                float4 xv = ((const float4*)(xs + kk * D_))[c + j * 4];
                acc[kk] += w.x*xv.x + w.y*xv.y + w.z*xv.z + w.w*xv.w;
            }
        }
        #pragma unroll
        for (int kk = 0; kk < 6; ++kk) {
            acc[kk] += __shfl_xor(acc[kk], 1);
            acc[kk] += __shfl_xor(acc[kk], 2);
        }
        if (c == 0) {
            const float bias = b_in[D_ + eh];
            const int isV = eh >> 8;
            const int ee = eh & 255;
            const int h = ee >> 5, d = ee & 31;
            float* dstp = ws + (isV ? OFF_VG : OFF_KG) + ((b * H_ + h) * K_) * HD_ + d;
            #pragma unroll
            for (int kk = 0; kk < 6; ++kk) dstp[(j0 + kk) * HD_] = acc[kk] + bias;
        }
    }
}

// ---------------- kernel 4: tiled fp32 GEMM with register prefetch ----------------
// C[M,256] = A[M,256] * W[256,256]^T + bias. BM=BN=64, BK=32, 4x4 microtile.
__global__ __launch_bounds__(256) void gemm_kernel(
    const float* __restrict__ A, const float* __restrict__ W,
    const float* __restrict__ bias, float* __restrict__ C)
{
    const int m0 = blockIdx.x * 64;
    const int n0 = blockIdx.y * 64;
    const int tid = threadIdx.x;
    __shared__ __align__(16) float As[32 * 68];
    __shared__ __align__(16) float Bs[32 * 68];
    const int tm = tid & 15, tn = tid >> 4;
    const int row = tid >> 3, dc = tid & 7;

    const float* Ap = A + (size_t)(m0 + row) * D_ + dc * 4;
    const float* Wp = W + (size_t)(n0 + row) * D_ + dc * 4;
    float4 a0 = *(const float4*)Ap;
    float4 a1 = *(const float4*)(Ap + 32 * D_);
    float4 w0 = *(const float4*)Wp;
    float4 w1 = *(const float4*)(Wp + 32 * D_);

    float4 acc0 = {0,0,0,0}, acc1 = {0,0,0,0}, acc2 = {0,0,0,0}, acc3 = {0,0,0,0};

    for (int k0 = 0; k0 < D_; k0 += 32) {
        __syncthreads();
        As[(dc*4+0)*68 + row] = a0.x; As[(dc*4+1)*68 + row] = a0.y;
        As[(dc*4+2)*68 + row] = a0.z; As[(dc*4+3)*68 + row] = a0.w;
        As[(dc*4+0)*68 + row+32] = a1.x; As[(dc*4+1)*68 + row+32] = a1.y;
        As[(dc*4+2)*68 + row+32] = a1.z; As[(dc*4+3)*68 + row+32] = a1.w;
        Bs[(dc*4+0)*68 + row] = w0.x; Bs[(dc*4+1)*68 + row] = w0.y;
        Bs[(dc*4+2)*68 + row] = w0.z; Bs[(dc*4+3)*68 + row] = w0.w;
        Bs[(dc*4+0)*68 + row+32] = w1.x; Bs[(dc*4+1)*68 + row+32] = w1.y;
        Bs[(dc*4+2)*68 + row+32] = w1.z; Bs[(dc*4+3)*68 + row+32] = w1.w;
        __syncthreads();
        if (k0 < D_ - 32) {   // prefetch next k-tile; waits land at next iter's stores
            a0 = *(const float4*)(Ap + k0 + 32);
            a1 = *(const float4*)(Ap + 32 * D_ + k0 + 32);
            w0 = *(const float4*)(Wp + k0 + 32);
            w1 = *(const float4*)(Wp + 32 * D_ + k0 + 32);
        }
        #pragma unroll
        for (int k = 0; k < 32; ++k) {
            float4 a4 = *(const float4*)&As[k*68 + tm*4];
            float4 b4 = *(const float4*)&Bs[k*68 + tn*4];
            acc0.x += a4.x*b4.x; acc0.y += a4.x*b4.y; acc0.z += a4.x*b4.z; acc0.w += a4.x*b4.w;
            acc1.x += a4.y*b4.x; acc1.y += a4.y*b4.y; acc1.z += a4.y*b4.z; acc1.w += a4.y*b4.w;
            acc2.x += a4.z*b4.x; acc2.y += a4.z*b4.y; acc2.z += a4.z*b4.z; acc2.w += a4.z*b4.w;
            acc3.x += a4.w*b4.x; acc3.y += a4.w*b4.y; acc3.z += a4.w*b4.z; acc3.w += a4.w*b4.w;
        }
    }
    float4 bi = *(const float4*)(bias + n0 + tn*4);
    float4 o;
    o.x = acc0.x+bi.x; o.y = acc0.y+bi.y; o.z = acc0.z+bi.z; o.w = acc0.w+bi.w;
    *(float4*)(C + (size_t)(m0 + tm*4 + 0) * D_ + n0 + tn*4) = o;
    o.x = acc1.x+bi.x; o.y = acc1.y+bi.y; o.z = acc1.z+bi.z; o.w = acc1.w+bi.w;
    *(float4*)(C + (size_t)(m0 + tm*4 + 1) * D_ + n0 + tn*4) = o;
    o.x = acc2.x+bi.x; o.y = acc2.y+bi.y; o.z = acc2.z+bi.z; o.w = acc2.w+bi.w;
    *(float4*)(C + (size_t)(m0 + tm*4 + 2) * D_ + n0 + tn*4) = o;
    o.x = acc3.x+bi.x; o.y = acc3.y+bi.y; o.z = acc3.z+bi.z; o.w = acc3.w+bi.w;
    *(float4*)(C + (size_t)(m0 + tm*4 + 3) * D_ + n0 + tn*4) = o;
}

// ---------------- kernel 5: attention core (low-LDS, high-occupancy) ----------------
// one block per (32-query tile, head, batch). K transposed in LDS (overlaid by
// exp-scores after use); V read straight from L2; per-wave query partition for PV.
#define KSTR 208
__global__ __launch_bounds__(256) void attn_kernel(const float* __restrict__ ws, float* __restrict__ ao)
{
    const int b = blockIdx.z, h = blockIdx.y, q0 = blockIdx.x * 32;
    const int tid = threadIdx.x;
    __shared__ __align__(16) float Kt[32 * KSTR];  // Kt[d][j]; overlaid by Ss[j][q]
    __shared__ __align__(16) float Qt[32 * 36];    // Qt[d][q]
    __shared__ float red[8 * 32];
    __shared__ float inv[32];

    const float4* kg = (const float4*)(ws + OFF_KG + ((b * H_ + h) * K_) * HD_);
    for (int i = tid; i < K_ * 8; i += 256) {
        const int j = i >> 3, dcc = i & 7;
        float4 kv = kg[i];
        Kt[(dcc*4+0)*KSTR + j] = kv.x;
        Kt[(dcc*4+1)*KSTR + j] = kv.y;
        Kt[(dcc*4+2)*KSTR + j] = kv.z;
        Kt[(dcc*4+3)*KSTR + j] = kv.w;
    }
    {
        const int q = tid >> 3, dcc = tid & 7;
        float4 qv = *(const float4*)(ws + OFF_Q + (size_t)(b * S_ + q0 + q) * D_ + h * HD_ + dcc * 4);
        Qt[(dcc*4+0)*36 + q] = qv.x;
        Qt[(dcc*4+1)*36 + q] = qv.y;
        Qt[(dcc*4+2)*36 + q] = qv.z;
        Qt[(dcc*4+3)*36 + q] = qv.w;
    }
    __syncthreads();

    // scores: virtual threads w in [0,408) = (jg in [0,51)) x (qg in [0,8))
    // exp in-register (scores bounded; exp(s)/sum == exp(s-m)/sum up to rounding)
    float4 e0[4], e1[4];
    {
        const int jg = tid >> 3, qg = tid & 7;
        float4 a0 = {0,0,0,0}, a1 = {0,0,0,0}, a2 = {0,0,0,0}, a3 = {0,0,0,0};
        #pragma unroll 8
        for (int d = 0; d < 32; ++d) {
            float4 kf = *(const float4*)&Kt[d*KSTR + jg*4];
            float4 qf = *(const float4*)&Qt[d*36 + qg*4];
            a0.x += kf.x*qf.x; a0.y += kf.x*qf.y; a0.z += kf.x*qf.z; a0.w += kf.x*qf.w;
            a1.x += kf.y*qf.x; a1.y += kf.y*qf.y; a1.z += kf.y*qf.z; a1.w += kf.y*qf.w;
            a2.x += kf.z*qf.x; a2.y += kf.z*qf.y; a2.z += kf.z*qf.z; a2.w += kf.z*qf.w;
            a3.x += kf.w*qf.x; a3.y += kf.w*qf.y; a3.z += kf.w*qf.z; a3.w += kf.w*qf.w;
        }
        e0[0].x = __expf(a0.x*SCALE_); e0[0].y = __expf(a0.y*SCALE_); e0[0].z = __expf(a0.z*SCALE_); e0[0].w = __expf(a0.w*SCALE_);
        e0[1].x = __expf(a1.x*SCALE_); e0[1].y = __expf(a1.y*SCALE_); e0[1].z = __expf(a1.z*SCALE_); e0[1].w = __expf(a1.w*SCALE_);
        e0[2].x = __expf(a2.x*SCALE_); e0[2].y = __expf(a2.y*SCALE_); e0[2].z = __expf(a2.z*SCALE_); e0[2].w = __expf(a2.w*SCALE_);
        e0[3].x = __expf(a3.x*SCALE_); e0[3].y = __expf(a3.y*SCALE_); e0[3].z = __expf(a3.z*SCALE_); e0[3].w = __expf(a3.w*SCALE_);
    }
    if (tid < 152) {
        const int w = 256 + tid;
        const int jg = w >> 3, qg = w & 7;
        float4 a0 = {0,0,0,0}, a1 = {0,0,0,0}, a2 = {0,0,0,0}, a3 = {0,0,0,0};
        #pragma unroll 8
        for (int d = 0; d < 32; ++d) {
            float4 kf = *(const float4*)&Kt[d*KSTR + jg*4];
            float4 qf = *(const float4*)&Qt[d*36 + qg*4];
            a0.x += kf.x*qf.x; a0.y += kf.x*qf.y; a0.z += kf.x*qf.z; a0.w += kf.x*qf.w;
            a1.x += kf.y*qf.x; a1.y += kf.y*qf.y; a1.z += kf.y*qf.z; a1.w += kf.y*qf.w;
            a2.x += kf.z*qf.x; a2.y += kf.z*qf.y; a2.z += kf.z*qf.z; a2.w += kf.z*qf.w;
            a3.x += kf.w*qf.x; a3.y += kf.w*qf.y; a3.z += kf.w*qf.z; a3.w += kf.w*qf.w;
        }
        e1[0].x = __expf(a0.x*SCALE_); e1[0].y = __expf(a0.y*SCALE_); e1[0].z = __expf(a0.z*SCALE_); e1[0].w = __expf(a0.w*SCALE_);
        e1[1].x = __expf(a1.x*SCALE_); e1[1].y = __expf(a1.y*SCALE_); e1[1].z = __expf(a1.z*SCALE_); e1[1].w = __expf(a1.w*SCALE_);
        e1[2].x = __expf(a2.x*SCALE_); e1[2].y = __expf(a2.y*SCALE_); e1[2].z = __expf(a2.z*SCALE_); e1[2].w = __expf(a2.w*SCALE_);
        e1[3].x = __expf(a3.x*SCALE_); e1[3].y = __expf(a3.y*SCALE_); e1[3].z = __expf(a3.z*SCALE_); e1[3].w = __expf(a3.w*SCALE_);
    }
    __syncthreads();   // all Kt reads complete before overlay

    float* Ss = Kt;    // Ss[j*32 + q], 6528 floats <= 32*KSTR
    {
        const int jg = tid >> 3, qg = tid & 7;
        *(float4*)&Ss[(jg*4+0)*32 + qg*4] = e0[0];
        *(float4*)&Ss[(jg*4+1)*32 + qg*4] = e0[1];
        *(float4*)&Ss[(jg*4+2)*32 + qg*4] = e0[2];
        *(float4*)&Ss[(jg*4+3)*32 + qg*4] = e0[3];
    }
    if (tid < 152) {
        const int w = 256 + tid;
        const int jg = w >> 3, qg = w & 7;
        *(float4*)&Ss[(jg*4+0)*32 + qg*4] = e1[0];
        *(float4*)&Ss[(jg*4+1)*32 + qg*4] = e1[1];
        *(float4*)&Ss[(jg*4+2)*32 + qg*4] = e1[2];
        *(float4*)&Ss[(jg*4+3)*32 + qg*4] = e1[3];
    }
    __syncthreads();

    // softmax denominator
    {
        const int q = tid & 31, l = tid >> 5;
        float s = 0.0f;
        const int nt = (l < 4) ? 26 : 25;
        for (int t = 0; t < nt; ++t) s += Ss[(l + 8*t)*32 + q];
        red[l*32 + q] = s;
    }
    __syncthreads();
    if (tid < 32) {
        float s = 0.0f;
        #pragma unroll
        for (int l = 0; l < 8; ++l) s += red[l*32 + tid];
        inv[tid] = 1.0f / s;
    }
    __syncthreads();

    // PV: wave wv owns queries [8*wv, 8*wv+8); V streamed from L2; no cross-wave reduce
    {
        const int wv = tid >> 6, lane = tid & 63;
        const int qq = lane >> 3, dg = lane & 7;
        const int q = wv * 8 + qq;
        const float* vgp = ws + OFF_VG + ((b * H_ + h) * K_) * HD_ + dg * 4;
        const float* sq = Ss + q;
        float4 A0 = {0,0,0,0}, A1 = {0,0,0,0}, A2 = {0,0,0,0}, A3 = {0,0,0,0};
        for (int j = 0; j < K_; j += 4) {
            float s0 = sq[(j+0)*32], s1 = sq[(j+1)*32], s2 = sq[(j+2)*32], s3 = sq[(j+3)*32];
            float4 v0 = *(const float4*)(vgp + (j+0)*HD_);
            float4 v1 = *(const float4*)(vgp + (j+1)*HD_);
            float4 v2 = *(const float4*)(vgp + (j+2)*HD_);
            float4 v3 = *(const float4*)(vgp + (j+3)*HD_);
            A0.x += s0*v0.x; A0.y += s0*v0.y; A0.z += s0*v0.z; A0.w += s0*v0.w;
            A1.x += s1*v1.x; A1.y += s1*v1.y; A1.z += s1*v1.z; A1.w += s1*v1.w;
            A2.x += s2*v2.x; A2.y += s2*v2.y; A2.z += s2*v2.z; A2.w += s2*v2.w;
            A3.x += s3*v3.x; A3.y += s3*v3.y; A3.z += s3*v3.z; A3.w += s3*v3.w;
        }
        const float iv = inv[q];
        float4 o;
        o.x = ((A0.x+A1.x)+(A2.x+A3.x)) * iv;
        o.y = ((A0.y+A1.y)+(A2.y+A3.y)) * iv;
        o.z = ((A0.z+A1.z)+(A2.z+A3.z)) * iv;
        o.w = ((A0.w+A1.w)+(A2.w+A3.w)) * iv;
        *(float4*)(ao + (size_t)(b * S_ + q0 + q) * D_ + h * HD_ + dg * 4) = o;
    }
}

extern "C" void kernel_launch(void* const* d_in, const int* in_sizes, int n_in,
                              void* d_out, int out_size, void* d_ws, size_t ws_size,
                              hipStream_t stream)
{
    const float* x     = (const float*)d_in[0];
    const float* w_in  = (const float*)d_in[1];
    const float* b_in  = (const float*)d_in[2];
    const float* w_out = (const float*)d_in[3];
    const float* b_out = (const float*)d_in[4];
    const float* gw1   = (const float*)d_in[5];
    const float* gb1   = (const float*)d_in[6];
    const float* gw2   = (const float*)d_in[7];
    // d_in[8] = gate_b2: constant inside monotone sigmoid -> doesn't affect top-k

    float* ws = (float*)d_ws;
    int* flags = (int*)(ws + OFF_FLAGS);
    int* kidx  = (int*)(ws + OFF_KIDX);
    float* out = (float*)d_out;

    gate_kernel<<<B_ * S_ / 32, 256, 0, stream>>>(x, gw1, gb1, gw2, ws);
    rank_kernel<<<B_ * 8, 256, 0, stream>>>(ws + OFF_IMP, flags);
    emit_kernel<<<B_, 256, 0, stream>>>(flags, kidx);
    kv_kernel<<<dim3(34, B_), 256, 0, stream>>>(x, w_in, b_in, ws, kidx);
    // Q = x @ w_in[0:256]^T + b_in[0:256]
    gemm_kernel<<<dim3(B_ * S_ / 64, D_ / 64), 256, 0, stream>>>(x, w_in, b_in, ws + OFF_Q);
    attn_kernel<<<dim3(S_ / 32, H_, B_), 256, 0, stream>>>(ws, ws + OFF_AO);
    // out = AO @ w_out^T + b_out
    gemm_kernel<<<dim3(B_ * S_ / 64, D_ / 64), 256, 0, stream>>>(ws + OFF_AO, w_out, b_out, out);
}